// Round 7
// baseline (164.933 us; speedup 1.0000x reference)
//
#include <hip/hip_runtime.h>

// CMDNet (M=2, m={-1,+1}, equal alpha) — MFMA HH + packed-f16 DPP matvec,
// register-slimmed for 8 waves/SIMD.
//
// R6 lesson: true footprint was 56 VGPR + 32 AGPR (two MFMA accs) ≈ 88 regs
// -> only ~3 waves/SIMD resident (Occupancy 36%), latency-bound at VALUBusy 72%.
// This version: ONE MFMA acc (16 AGPR, batches sequential) + own_d stored as
// 16 packed-f16 regs consumed by v_fma_mix_f32 + (xt,xts) packed in one reg so
// ONE dpp mov rotates both column blocks. Target <=64 total regs -> (256,8).
//
// Precision: f16 storage of HH rows / x (RTZ) adds ~1e-3 to r, ~1e-4 to ft —
// threshold is 1.77e-2 and checker granularity 2^-8. MFMA itself stays
// bf16 hi/lo split (err ~2^-17). Epilogue uses xt = tanh(z/2) identity,
// 2*ft0*ft1 = (1-xt^2)/2 — algebraically exact vs reference softmax.
//
// Tripwire: if FETCH >> 68 MB or WRITE >> 6 MB, the 64-reg cap spilled ->
// fall back to __launch_bounds__(256,6).

#define NRX 64
#define KSYM 32

typedef float  f32x16 __attribute__((ext_vector_type(16)));
typedef short  short8 __attribute__((ext_vector_type(8)));

__device__ __forceinline__ float readlane_f(float v, int lane) {
    return __int_as_float(__builtin_amdgcn_readlane(__float_as_int(v), lane));
}
__device__ __forceinline__ unsigned cvt_pk_bf16(float a, float b) {
    unsigned r;
    asm("v_cvt_pk_bf16_f32 %0, %1, %2" : "=v"(r) : "v"(a), "v"(b));
    return r;
}
__device__ __forceinline__ int cvt_pk_f16(float a, float b) {  // RTZ pack
    int r;
    asm("v_cvt_pkrtz_f16_f32 %0, %1, %2" : "=v"(r) : "v"(a), "v"(b));
    return r;
}
template <int N>
__device__ __forceinline__ int dpp_ror_i(int v) {
    return __builtin_amdgcn_update_dpp(0, v, 0x120 + N, 0xF, 0xF, true);
}
// acc += f16lo(o) * f16lo(x)   /   acc += f16hi(o) * f16hi(x)
#define MIXLO(acc, o, x) asm("v_fma_mix_f32 %0, %1, %2, %0 op_sel:[0,0,0] op_sel_hi:[1,1,0]" : "+v"(acc) : "v"(o), "v"(x))
#define MIXHI(acc, o, x) asm("v_fma_mix_f32 %0, %1, %2, %0 op_sel:[1,1,0] op_sel_hi:[1,1,0]" : "+v"(acc) : "v"(o), "v"(x))

union FragU { unsigned u[4]; short8 s; };

__global__ __launch_bounds__(256, 8) void cmdnet_kernel(
    const float* __restrict__ yt,      // [B,64]
    const float* __restrict__ Ht,      // [B,64,32]
    const float* __restrict__ sigmat0, // [B]
    const float* __restrict__ taui,    // [niter+1]
    const float* __restrict__ delta,   // [niter]
    float* __restrict__ out_ft,        // [B,32,2]
    float* __restrict__ out_xt,        // [B,32]
    int niter)
{
    __shared__ __align__(16) float hhbuf[4][KSYM * KSYM];  // 16 KB (4 KB/wave)
    __shared__ __align__(16) float ytL[4][2][NRX];         // 2 KB

    const int tid  = threadIdx.x;
    const int w    = tid >> 6;
    const int lane = tid & 63;
    const int k    = lane & 31;
    const int h    = lane >> 5;
    const int hi8  = h * 8;
    const int bb   = blockIdx.x * 8 + w * 2;
    const int b    = bb + h;

    ytL[w][0][lane] = yt[(size_t)bb * NRX + lane];
    ytL[w][1][lane] = yt[(size_t)bb * NRX + NRX + lane];

    float dreg = 0.f, treg = 1.f;
    if (lane < niter) { dreg = delta[lane]; treg = fabsf(taui[lane + 1]); }

    float sig2 = sigmat0[b];
    sig2 *= sig2;

    float* buf = &hhbuf[w][0];
    const int low4 = k & 15;
    int own_pk[16];           // packed f16: lo = HH[k][(k&16)|perm_j], hi = other block
    float yhp0 = 0.f, yhp1 = 0.f;

    // ---- Phase 1: per batch s: MFMA HH (one shared acc) -> LDS -> f16 gather ----
    #pragma unroll
    for (int s = 0; s < 2; ++s) {
        f32x16 acc;
        #pragma unroll
        for (int j = 0; j < 16; ++j) acc[j] = 0.f;

        const float* Hb = Ht + ((size_t)(bb + s)) * (NRX * KSYM);
        #pragma unroll
        for (int c = 0; c < 4; ++c) {
            const float* base = Hb + (c * 16 + hi8) * KSYM + k;
            float f[8];
            #pragma unroll
            for (int e = 0; e < 8; ++e) f[e] = base[e * KSYM];

            float4 ya = *reinterpret_cast<const float4*>(&ytL[w][s][c * 16 + hi8]);
            float4 yb = *reinterpret_cast<const float4*>(&ytL[w][s][c * 16 + hi8 + 4]);
            float yp = (s == 0) ? yhp0 : yhp1;
            yp = fmaf(ya.x, f[0], yp); yp = fmaf(ya.y, f[1], yp);
            yp = fmaf(ya.z, f[2], yp); yp = fmaf(ya.w, f[3], yp);
            yp = fmaf(yb.x, f[4], yp); yp = fmaf(yb.y, f[5], yp);
            yp = fmaf(yb.z, f[6], yp); yp = fmaf(yb.w, f[7], yp);
            if (s == 0) yhp0 = yp; else yhp1 = yp;

            FragU hiF, loF;
            #pragma unroll
            for (int p = 0; p < 4; ++p) {
                unsigned hp = cvt_pk_bf16(f[2*p], f[2*p+1]);
                float h0 = __uint_as_float(hp << 16);
                float h1 = __uint_as_float(hp & 0xffff0000u);
                loF.u[p] = cvt_pk_bf16(f[2*p] - h0, f[2*p+1] - h1);
                hiF.u[p] = hp;
            }
            acc = __builtin_amdgcn_mfma_f32_32x32x16_bf16(hiF.s, hiF.s, acc, 0, 0, 0);
            acc = __builtin_amdgcn_mfma_f32_32x32x16_bf16(hiF.s, loF.s, acc, 0, 0, 0);
            acc = __builtin_amdgcn_mfma_f32_32x32x16_bf16(loF.s, hiF.s, acc, 0, 0, 0);
        }

        // acc -> LDS (C/D layout: col=lane&31, row=(j&3)+8*(j>>2)+4*h)
        #pragma unroll
        for (int j = 0; j < 16; ++j) {
            int row = (j & 3) + 8 * (j >> 2) + 4 * h;
            buf[row * 32 + k] = acc[j];
        }
        // lanes of batch s gather their diagonal-permuted row, packed to f16.
        // (h==s mask is 32-lane aligned -> DPP row sources all enabled)
        if (h == s) {
            const float* rowp = buf + k * 32;
            own_pk[0] = cvt_pk_f16(rowp[k], rowp[k ^ 16]);
            #define GATH(J) { \
                int idx = dpp_ror_i<J>(low4); \
                own_pk[J] = cvt_pk_f16(rowp[(k & 16) | idx], rowp[((k & 16) ^ 16) | idx]); }
            GATH(1)  GATH(2)  GATH(3)  GATH(4)  GATH(5)
            GATH(6)  GATH(7)  GATH(8)  GATH(9)  GATH(10)
            GATH(11) GATH(12) GATH(13) GATH(14) GATH(15)
            #undef GATH
        }
    }

    float yh0 = yhp0 + __shfl_xor(yhp0, 32, 64);
    float yh1 = yhp1 + __shfl_xor(yhp1, 32, 64);
    float yh  = h ? yh1 : yh0;

    // ---- Phase 3: iterations — packed-f16 DPP matvec, ft-free epilogue ----
    float tau = fabsf(taui[0]);
    float G0 = 0.f, G1 = 0.f;
    float xt = 0.f;

    for (int i = 0; i < niter; ++i) {
        float d        = readlane_f(dreg, i);
        float tau_next = readlane_f(treg, i);

        // pack (xt, xt^16-partner) as f16x2; one DPP rotates both blocks
        float xts = __int_as_float(
            __builtin_amdgcn_ds_swizzle(__float_as_int(xt), 0x401F)); // xor 16
        int xpk = cvt_pk_f16(xt, xts);

        float a0 = -yh, a1 = 0.f, a2 = 0.f, a3 = 0.f;
        MIXLO(a0, own_pk[0], xpk);
        MIXHI(a1, own_pk[0], xpk);
        #define STEP(J) { \
            int xr = dpp_ror_i<J>(xpk); \
            if ((J) & 1) { MIXLO(a2, own_pk[J], xr); MIXHI(a3, own_pk[J], xr); } \
            else         { MIXLO(a0, own_pk[J], xr); MIXHI(a1, own_pk[J], xr); } }
        STEP(1)  STEP(2)  STEP(3)  STEP(4)  STEP(5)
        STEP(6)  STEP(7)  STEP(8)  STEP(9)  STEP(10)
        STEP(11) STEP(12) STEP(13) STEP(14) STEP(15)
        #undef STEP
        float r = (a0 + a2) + (a1 + a3);

        // p = 2*tau*ft0*ft1*r = 0.5*tau*(1-xt^2)*r
        float t  = fmaf(-xt, xt, 1.0f);
        float p  = 0.5f * tau * t * r;
        float e0 = __expf(-G0);
        float e1 = __expf(-G1);
        float g0 = fmaf(sig2, 1.f - e0, -p);
        float g1 = fmaf(sig2, 1.f - e1,  p);
        G0 = fmaf(-d, g0, G0);
        G1 = fmaf(-d, g1, G1);

        tau = tau_next;
        float z  = tau * (G1 - G0);
        float ez = __expf(-fabsf(z));
        float sg = __builtin_amdgcn_rcpf(1.f + ez);
        float m  = (1.f - ez) * sg;           // |tanh(z/2)|
        xt = __builtin_copysignf(m, z);
    }

    // ---- outputs: ft1 = (1+xt)/2, ft0 = (1-xt)/2 ----
    float ft1 = fmaf(0.5f, xt, 0.5f);
    float ft0 = 1.f - ft1;
    float2 f2 = make_float2(ft0, ft1);
    reinterpret_cast<float2*>(out_ft)[(size_t)b * KSYM + k] = f2;
    out_xt[(size_t)b * KSYM + k] = xt;
}

extern "C" void kernel_launch(void* const* d_in, const int* in_sizes, int n_in,
                              void* d_out, int out_size, void* d_ws, size_t ws_size,
                              hipStream_t stream) {
    const float* yt    = (const float*)d_in[0];
    const float* Ht    = (const float*)d_in[1];
    const float* sg    = (const float*)d_in[2];
    const float* taui  = (const float*)d_in[3];
    const float* delta = (const float*)d_in[4];
    int B     = in_sizes[2];
    int niter = in_sizes[4];
    float* out    = (float*)d_out;
    float* out_ft = out;
    float* out_xt = out + (size_t)B * 64;

    dim3 grid(B / 8), block(256);
    hipLaunchKernelGGL(cmdnet_kernel, grid, block, 0, stream,
                       yt, Ht, sg, taui, delta, out_ft, out_xt, niter);
}

// Round 8
// 125.437 us; speedup vs baseline: 1.3149x; 1.3149x over previous
//
#include <hip/hip_runtime.h>

// CMDNet (M=2, m={-1,+1}, equal alpha) — MFMA HH + packed-f16 dot2 DPP matvec.
//
// Operating point (R2/R3/R5/R7 lessons): NEVER request 8 waves/EU (16-AGPR
// acc + staging ≈ 72 total regs can't fit a 64-cap; spill = FETCH/WRITE
// explosion). This round: (256,6) -> cap 85 >= 72 needed, 6 waves/SIMD.
//
// Loop matvec now uses v_dot2_f32_f16 (2 f16 MACs, f32 accumulate): own_pk[j]
// holds (HH[k][blkA|perm_j], HH[k][blkB|perm_j]) as f16x2, xpk holds the
// matching (x_blkA, x_blkB) rotated by the SAME dpp ctrl -> one instruction
// per j instead of MIXLO+MIXHI. Same f16-input/f32-acc precision as R6/R7
// (passed, absmax 3.9e-3 vs threshold 1.77e-2).
//
// Phase 1 unchanged: HH = Ht^T Ht via v_mfma_f32_32x32x16_bf16, bf16 hi/lo
// split (err ~2^-17), one 16-AGPR acc reused across the 2 batches; yH via
// VALU partials. Epilogue ft-free: xt = tanh(z/2), 2*ft0*ft1 = (1-xt^2)/2.

#define NRX 64
#define KSYM 32

typedef float  f32x16 __attribute__((ext_vector_type(16)));
typedef short  short8 __attribute__((ext_vector_type(8)));
typedef _Float16 h16x2 __attribute__((ext_vector_type(2)));

__device__ __forceinline__ float readlane_f(float v, int lane) {
    return __int_as_float(__builtin_amdgcn_readlane(__float_as_int(v), lane));
}
__device__ __forceinline__ unsigned cvt_pk_bf16(float a, float b) {
    unsigned r;
    asm("v_cvt_pk_bf16_f32 %0, %1, %2" : "=v"(r) : "v"(a), "v"(b));
    return r;
}
__device__ __forceinline__ int cvt_pk_f16(float a, float b) {  // RTZ pack
    int r;
    asm("v_cvt_pkrtz_f16_f32 %0, %1, %2" : "=v"(r) : "v"(a), "v"(b));
    return r;
}
template <int N>
__device__ __forceinline__ int dpp_ror_i(int v) {
    return __builtin_amdgcn_update_dpp(0, v, 0x120 + N, 0xF, 0xF, true);
}
__device__ __forceinline__ float dot2_f16(int a, int b, float c) {
#if __has_builtin(__builtin_amdgcn_fdot2)
    union { int i; h16x2 h; } ua, ub;
    ua.i = a; ub.i = b;
    return __builtin_amdgcn_fdot2(ua.h, ub.h, c, false);
#else
    float r = c;
    asm("v_dot2_f32_f16 %0, %1, %2, %0" : "+v"(r) : "v"(a), "v"(b));
    return r;
#endif
}

union FragU { unsigned u[4]; short8 s; };

__global__ __launch_bounds__(256, 6) void cmdnet_kernel(
    const float* __restrict__ yt,      // [B,64]
    const float* __restrict__ Ht,      // [B,64,32]
    const float* __restrict__ sigmat0, // [B]
    const float* __restrict__ taui,    // [niter+1]
    const float* __restrict__ delta,   // [niter]
    float* __restrict__ out_ft,        // [B,32,2]
    float* __restrict__ out_xt,        // [B,32]
    int niter)
{
    __shared__ __align__(16) float hhbuf[4][KSYM * KSYM];  // 16 KB (4 KB/wave)
    __shared__ __align__(16) float ytL[4][2][NRX];         // 2 KB

    const int tid  = threadIdx.x;
    const int w    = tid >> 6;
    const int lane = tid & 63;
    const int k    = lane & 31;
    const int h    = lane >> 5;
    const int hi8  = h * 8;
    const int bb   = blockIdx.x * 8 + w * 2;
    const int b    = bb + h;

    ytL[w][0][lane] = yt[(size_t)bb * NRX + lane];
    ytL[w][1][lane] = yt[(size_t)bb * NRX + NRX + lane];

    float dreg = 0.f, treg = 1.f;
    if (lane < niter) { dreg = delta[lane]; treg = fabsf(taui[lane + 1]); }

    float sig2 = sigmat0[b];
    sig2 *= sig2;

    float* buf = &hhbuf[w][0];
    const int low4 = k & 15;
    int own_pk[16];           // f16x2: lo = HH[k][(k&16)|perm_j], hi = other block
    float yhp0 = 0.f, yhp1 = 0.f;

    // ---- Phase 1: per batch s: MFMA HH (one shared acc) -> LDS -> f16 gather ----
    #pragma unroll
    for (int s = 0; s < 2; ++s) {
        f32x16 acc;
        #pragma unroll
        for (int j = 0; j < 16; ++j) acc[j] = 0.f;

        const float* Hb = Ht + ((size_t)(bb + s)) * (NRX * KSYM);
        #pragma unroll
        for (int c = 0; c < 4; ++c) {
            const float* base = Hb + (c * 16 + hi8) * KSYM + k;
            float f[8];
            #pragma unroll
            for (int e = 0; e < 8; ++e) f[e] = base[e * KSYM];

            float4 ya = *reinterpret_cast<const float4*>(&ytL[w][s][c * 16 + hi8]);
            float4 yb = *reinterpret_cast<const float4*>(&ytL[w][s][c * 16 + hi8 + 4]);
            float yp = (s == 0) ? yhp0 : yhp1;
            yp = fmaf(ya.x, f[0], yp); yp = fmaf(ya.y, f[1], yp);
            yp = fmaf(ya.z, f[2], yp); yp = fmaf(ya.w, f[3], yp);
            yp = fmaf(yb.x, f[4], yp); yp = fmaf(yb.y, f[5], yp);
            yp = fmaf(yb.z, f[6], yp); yp = fmaf(yb.w, f[7], yp);
            if (s == 0) yhp0 = yp; else yhp1 = yp;

            FragU hiF, loF;
            #pragma unroll
            for (int p = 0; p < 4; ++p) {
                unsigned hp = cvt_pk_bf16(f[2*p], f[2*p+1]);
                float h0 = __uint_as_float(hp << 16);
                float h1 = __uint_as_float(hp & 0xffff0000u);
                loF.u[p] = cvt_pk_bf16(f[2*p] - h0, f[2*p+1] - h1);
                hiF.u[p] = hp;
            }
            acc = __builtin_amdgcn_mfma_f32_32x32x16_bf16(hiF.s, hiF.s, acc, 0, 0, 0);
            acc = __builtin_amdgcn_mfma_f32_32x32x16_bf16(hiF.s, loF.s, acc, 0, 0, 0);
            acc = __builtin_amdgcn_mfma_f32_32x32x16_bf16(loF.s, hiF.s, acc, 0, 0, 0);
        }

        // acc -> LDS (C/D layout: col=lane&31, row=(j&3)+8*(j>>2)+4*h)
        #pragma unroll
        for (int j = 0; j < 16; ++j) {
            int row = (j & 3) + 8 * (j >> 2) + 4 * h;
            buf[row * 32 + k] = acc[j];
        }
        // lanes of batch s gather their diagonal-permuted row, packed to f16
        // (h==s is 32-lane aligned -> DPP rows fully active; probed with the
        //  SAME dpp ctrl as the loop so layout agrees by construction)
        if (h == s) {
            const float* rowp = buf + k * 32;
            own_pk[0] = cvt_pk_f16(rowp[k], rowp[k ^ 16]);
            #define GATH(J) { \
                int idx = dpp_ror_i<J>(low4); \
                own_pk[J] = cvt_pk_f16(rowp[(k & 16) | idx], rowp[((k & 16) ^ 16) | idx]); }
            GATH(1)  GATH(2)  GATH(3)  GATH(4)  GATH(5)
            GATH(6)  GATH(7)  GATH(8)  GATH(9)  GATH(10)
            GATH(11) GATH(12) GATH(13) GATH(14) GATH(15)
            #undef GATH
        }
    }

    float yh0 = yhp0 + __shfl_xor(yhp0, 32, 64);
    float yh1 = yhp1 + __shfl_xor(yhp1, 32, 64);
    float yh  = h ? yh1 : yh0;

    // ---- Phase 3: iterations — dot2 DPP matvec, ft-free epilogue ----
    float tau = fabsf(taui[0]);
    float G0 = 0.f, G1 = 0.f;
    float xt = 0.f;

    for (int i = 0; i < niter; ++i) {
        float d        = readlane_f(dreg, i);
        float tau_next = readlane_f(treg, i);

        // pack (xt, xt^16-partner) as f16x2; one DPP rotates both blocks
        float xts = __int_as_float(
            __builtin_amdgcn_ds_swizzle(__float_as_int(xt), 0x401F)); // xor 16
        int xpk = cvt_pk_f16(xt, xts);

        float a0 = -yh, a1 = 0.f, a2 = 0.f, a3 = 0.f;
        a0 = dot2_f16(own_pk[0], xpk, a0);
        #define STEP(J) { \
            int xr = dpp_ror_i<J>(xpk); \
            float& aa = ((J) & 3) == 0 ? a0 : ((J) & 3) == 1 ? a1 : ((J) & 3) == 2 ? a2 : a3; \
            aa = dot2_f16(own_pk[J], xr, aa); }
        STEP(1)  STEP(2)  STEP(3)  STEP(4)  STEP(5)
        STEP(6)  STEP(7)  STEP(8)  STEP(9)  STEP(10)
        STEP(11) STEP(12) STEP(13) STEP(14) STEP(15)
        #undef STEP
        float r = (a0 + a1) + (a2 + a3);

        // p = 2*tau*ft0*ft1*r = 0.5*tau*(1-xt^2)*r
        float t  = fmaf(-xt, xt, 1.0f);
        float p  = 0.5f * tau * t * r;
        float e0 = __expf(-G0);
        float e1 = __expf(-G1);
        float g0 = fmaf(sig2, 1.f - e0, -p);
        float g1 = fmaf(sig2, 1.f - e1,  p);
        G0 = fmaf(-d, g0, G0);
        G1 = fmaf(-d, g1, G1);

        tau = tau_next;
        float z  = tau * (G1 - G0);
        float ez = __expf(-fabsf(z));
        float sg = __builtin_amdgcn_rcpf(1.f + ez);
        float m  = (1.f - ez) * sg;           // |tanh(z/2)|
        xt = __builtin_copysignf(m, z);
    }

    // ---- outputs: ft1 = (1+xt)/2, ft0 = (1-xt)/2 ----
    float ft1 = fmaf(0.5f, xt, 0.5f);
    float ft0 = 1.f - ft1;
    float2 f2 = make_float2(ft0, ft1);
    reinterpret_cast<float2*>(out_ft)[(size_t)b * KSYM + k] = f2;
    out_xt[(size_t)b * KSYM + k] = xt;
}

extern "C" void kernel_launch(void* const* d_in, const int* in_sizes, int n_in,
                              void* d_out, int out_size, void* d_ws, size_t ws_size,
                              hipStream_t stream) {
    const float* yt    = (const float*)d_in[0];
    const float* Ht    = (const float*)d_in[1];
    const float* sg    = (const float*)d_in[2];
    const float* taui  = (const float*)d_in[3];
    const float* delta = (const float*)d_in[4];
    int B     = in_sizes[2];
    int niter = in_sizes[4];
    float* out    = (float*)d_out;
    float* out_ft = out;
    float* out_xt = out + (size_t)B * 64;

    dim3 grid(B / 8), block(256);
    hipLaunchKernelGGL(cmdnet_kernel, grid, block, 0, stream,
                       yt, Ht, sg, taui, delta, out_ft, out_xt, niter);
}

// Round 10
// 105.309 us; speedup vs baseline: 1.5662x; 1.1911x over previous
//
#include <hip/hip_runtime.h>

// CMDNet (M=2, m={-1,+1}, equal alpha) — MFMA HH + dot2/DPP matvec, chain-slim.
//
// Operating point (R2/R3/R5/R7/R8): (256,4) ONLY. gfx950 occupancy quantizes
// at 64/128/256 total regs; this kernel needs ~72 (56 VGPR + 16 AGPR acc), so
// any waves_per_eu>4 ask clamps below footprint and spills (FETCH/WRITE
// explosion signature). At (256,4) we are VALU-issue/latency bound.
//
// R9 lesson: v_permlane16_swap_b32 via raw asm with two identical-valued
// "+v" operands got register-coalesced (swap-with-self, xt clobbered) ->
// absmax 8e-2. Cross-lane swaps MUST use the real builtin so the compiler
// models the dataflow. (A+B)-xt recovery is swap-direction robust.
//
// Loop: v_dot2_f32_f16 matvec (R8-proven), xor-16 exchange via
// __builtin_amdgcn_permlane16_swap (VALU) or ds_swizzle fallback,
// exp2-domain G (all v_exp without *log2e), 0.5 prefolded into own_pk/yh.
// Phase 1: HH = Ht^T Ht via v_mfma_f32_32x32x16_bf16, bf16 hi/lo split
// (err ~2^-17), ONE 16-AGPR acc reused across both batches; yH VALU partials.

#define NRX 64
#define KSYM 32

typedef float  f32x16 __attribute__((ext_vector_type(16)));
typedef short  short8 __attribute__((ext_vector_type(8)));
typedef _Float16 h16x2 __attribute__((ext_vector_type(2)));

__device__ __forceinline__ float readlane_f(float v, int lane) {
    return __int_as_float(__builtin_amdgcn_readlane(__float_as_int(v), lane));
}
__device__ __forceinline__ unsigned cvt_pk_bf16(float a, float b) {
    unsigned r;
    asm("v_cvt_pk_bf16_f32 %0, %1, %2" : "=v"(r) : "v"(a), "v"(b));
    return r;
}
__device__ __forceinline__ int cvt_pk_f16(float a, float b) {  // RTZ pack
    int r;
    asm("v_cvt_pkrtz_f16_f32 %0, %1, %2" : "=v"(r) : "v"(a), "v"(b));
    return r;
}
template <int N>
__device__ __forceinline__ int dpp_ror_i(int v) {
    return __builtin_amdgcn_update_dpp(0, v, 0x120 + N, 0xF, 0xF, true);
}
__device__ __forceinline__ float dot2_f16(int a, int b, float c) {
#if __has_builtin(__builtin_amdgcn_fdot2)
    union { int i; h16x2 h; } ua, ub;
    ua.i = a; ub.i = b;
    return __builtin_amdgcn_fdot2(ua.h, ub.h, c, false);
#else
    float r = c;
    asm("v_dot2_f32_f16 %0, %1, %2, %0" : "+v"(r) : "v"(a), "v"(b));
    return r;
#endif
}
__device__ __forceinline__ float exp2_fast(float x) {
#if __has_builtin(__builtin_amdgcn_exp2f)
    return __builtin_amdgcn_exp2f(x);
#else
    float r; asm("v_exp_f32 %0, %1" : "=v"(r) : "v"(x)); return r;
#endif
}
// partner value at lane^16, computed on the VALU where possible
__device__ __forceinline__ float xor16_f(float x) {
#if __has_builtin(__builtin_amdgcn_permlane16_swap)
    typedef unsigned uint2v __attribute__((ext_vector_type(2)));
    unsigned xi = __float_as_int(x);
    uint2v pr = __builtin_amdgcn_permlane16_swap(xi, xi, false, false);
    // exactly one of pr[0]/pr[1] holds the partner, the other holds x
    return (__uint_as_float(pr[0]) + __uint_as_float(pr[1])) - x;
#else
    return __int_as_float(
        __builtin_amdgcn_ds_swizzle(__float_as_int(x), 0x401F)); // xor 16
#endif
}

union FragU { unsigned u[4]; short8 s; };

__global__ __launch_bounds__(256, 4) void cmdnet_kernel(
    const float* __restrict__ yt,      // [B,64]
    const float* __restrict__ Ht,      // [B,64,32]
    const float* __restrict__ sigmat0, // [B]
    const float* __restrict__ taui,    // [niter+1]
    const float* __restrict__ delta,   // [niter]
    float* __restrict__ out_ft,        // [B,32,2]
    float* __restrict__ out_xt,        // [B,32]
    int niter)
{
    __shared__ __align__(16) float hhbuf[4][KSYM * KSYM];  // 16 KB (4 KB/wave)
    __shared__ __align__(16) float ytL[4][2][NRX];         // 2 KB

    const int tid  = threadIdx.x;
    const int w    = tid >> 6;
    const int lane = tid & 63;
    const int k    = lane & 31;
    const int h    = lane >> 5;
    const int hi8  = h * 8;
    const int bb   = blockIdx.x * 8 + w * 2;
    const int b    = bb + h;
    const float LOG2E = 1.4426950408889634f;

    ytL[w][0][lane] = yt[(size_t)bb * NRX + lane];
    ytL[w][1][lane] = yt[(size_t)bb * NRX + NRX + lane];

    // delta in exp2 domain; tau natural
    float dreg = 0.f, treg = 1.f;
    if (lane < niter) { dreg = delta[lane] * LOG2E; treg = fabsf(taui[lane + 1]); }

    float sig2 = sigmat0[b];
    sig2 *= sig2;

    float* buf = &hhbuf[w][0];
    const int low4 = k & 15;
    int own_pk[16];           // f16x2 of 0.5*HH: lo = blk(k&16)|perm_j, hi = other blk
    float yhp0 = 0.f, yhp1 = 0.f;

    // ---- Phase 1: per batch s: MFMA HH (one shared acc) -> LDS -> f16 gather ----
    #pragma unroll
    for (int s = 0; s < 2; ++s) {
        f32x16 acc;
        #pragma unroll
        for (int j = 0; j < 16; ++j) acc[j] = 0.f;

        const float* Hb = Ht + ((size_t)(bb + s)) * (NRX * KSYM);
        #pragma unroll
        for (int c = 0; c < 4; ++c) {
            const float* base = Hb + (c * 16 + hi8) * KSYM + k;
            float f[8];
            #pragma unroll
            for (int e = 0; e < 8; ++e) f[e] = base[e * KSYM];

            float4 ya = *reinterpret_cast<const float4*>(&ytL[w][s][c * 16 + hi8]);
            float4 yb = *reinterpret_cast<const float4*>(&ytL[w][s][c * 16 + hi8 + 4]);
            float yp = (s == 0) ? yhp0 : yhp1;
            yp = fmaf(ya.x, f[0], yp); yp = fmaf(ya.y, f[1], yp);
            yp = fmaf(ya.z, f[2], yp); yp = fmaf(ya.w, f[3], yp);
            yp = fmaf(yb.x, f[4], yp); yp = fmaf(yb.y, f[5], yp);
            yp = fmaf(yb.z, f[6], yp); yp = fmaf(yb.w, f[7], yp);
            if (s == 0) yhp0 = yp; else yhp1 = yp;

            FragU hiF, loF;
            #pragma unroll
            for (int p = 0; p < 4; ++p) {
                unsigned hp = cvt_pk_bf16(f[2*p], f[2*p+1]);
                float h0 = __uint_as_float(hp << 16);
                float h1 = __uint_as_float(hp & 0xffff0000u);
                loF.u[p] = cvt_pk_bf16(f[2*p] - h0, f[2*p+1] - h1);
                hiF.u[p] = hp;
            }
            acc = __builtin_amdgcn_mfma_f32_32x32x16_bf16(hiF.s, hiF.s, acc, 0, 0, 0);
            acc = __builtin_amdgcn_mfma_f32_32x32x16_bf16(hiF.s, loF.s, acc, 0, 0, 0);
            acc = __builtin_amdgcn_mfma_f32_32x32x16_bf16(loF.s, hiF.s, acc, 0, 0, 0);
        }

        // acc -> LDS (C/D layout: col=lane&31, row=(j&3)+8*(j>>2)+4*h)
        #pragma unroll
        for (int j = 0; j < 16; ++j) {
            int row = (j & 3) + 8 * (j >> 2) + 4 * h;
            buf[row * 32 + k] = acc[j];
        }
        // gather diagonal-permuted row, scaled by 0.5, packed f16
        // (probed with the SAME dpp ctrl as the loop -> layout agrees)
        if (h == s) {
            const float* rowp = buf + k * 32;
            own_pk[0] = cvt_pk_f16(0.5f * rowp[k], 0.5f * rowp[k ^ 16]);
            #define GATH(J) { \
                int idx = dpp_ror_i<J>(low4); \
                own_pk[J] = cvt_pk_f16(0.5f * rowp[(k & 16) | idx], \
                                       0.5f * rowp[((k & 16) ^ 16) | idx]); }
            GATH(1)  GATH(2)  GATH(3)  GATH(4)  GATH(5)
            GATH(6)  GATH(7)  GATH(8)  GATH(9)  GATH(10)
            GATH(11) GATH(12) GATH(13) GATH(14) GATH(15)
            #undef GATH
        }
    }

    float yh0 = yhp0 + __shfl_xor(yhp0, 32, 64);
    float yh1 = yhp1 + __shfl_xor(yhp1, 32, 64);
    float yh  = 0.5f * (h ? yh1 : yh0);   // pre-halved to match own_pk scale

    // ---- Phase 3: iterations ----
    float tau = fabsf(taui[0]);
    float Gl0 = 0.f, Gl1 = 0.f;           // G * log2e
    float xt = 0.f;

    for (int i = 0; i < niter; ++i) {
        float d2       = readlane_f(dreg, i);   // delta*log2e
        float tau_next = readlane_f(treg, i);

        float xts = xor16_f(xt);
        int xpk = cvt_pk_f16(xt, xts);

        float a0 = -yh, a1 = 0.f, a2 = 0.f, a3 = 0.f;
        a0 = dot2_f16(own_pk[0], xpk, a0);
        #define STEP(J) { \
            int xr = dpp_ror_i<J>(xpk); \
            float& aa = ((J) & 3) == 0 ? a0 : ((J) & 3) == 1 ? a1 : ((J) & 3) == 2 ? a2 : a3; \
            aa = dot2_f16(own_pk[J], xr, aa); }
        STEP(1)  STEP(2)  STEP(3)  STEP(4)  STEP(5)
        STEP(6)  STEP(7)  STEP(8)  STEP(9)  STEP(10)
        STEP(11) STEP(12) STEP(13) STEP(14) STEP(15)
        #undef STEP
        float r = (a0 + a1) + (a2 + a3);   // = 0.5*(xHH - yH)

        float t  = fmaf(-xt, xt, 1.0f);
        float p  = tau * t * r;            // = 2*tau*ft0*ft1*(xHH-yH)
        float e0 = exp2_fast(-Gl0);        // = exp(-G0)
        float e1 = exp2_fast(-Gl1);
        float g0 = fmaf(sig2, 1.f - e0, -p);
        float g1 = fmaf(sig2, 1.f - e1,  p);
        Gl0 = fmaf(-d2, g0, Gl0);
        Gl1 = fmaf(-d2, g1, Gl1);

        tau = tau_next;
        float z2 = tau * (Gl1 - Gl0);      // = log2e * z
        float ez = exp2_fast(-fabsf(z2));  // = exp(-|z|)
        float sg = __builtin_amdgcn_rcpf(1.f + ez);
        float m  = (1.f - ez) * sg;        // |tanh(z/2)|
        xt = __builtin_copysignf(m, z2);
    }

    // ---- outputs: ft1 = (1+xt)/2, ft0 = (1-xt)/2 ----
    float ft1 = fmaf(0.5f, xt, 0.5f);
    float ft0 = 1.f - ft1;
    float2 f2 = make_float2(ft0, ft1);
    reinterpret_cast<float2*>(out_ft)[(size_t)b * KSYM + k] = f2;
    out_xt[(size_t)b * KSYM + k] = xt;
}

extern "C" void kernel_launch(void* const* d_in, const int* in_sizes, int n_in,
                              void* d_out, int out_size, void* d_ws, size_t ws_size,
                              hipStream_t stream) {
    const float* yt    = (const float*)d_in[0];
    const float* Ht    = (const float*)d_in[1];
    const float* sg    = (const float*)d_in[2];
    const float* taui  = (const float*)d_in[3];
    const float* delta = (const float*)d_in[4];
    int B     = in_sizes[2];
    int niter = in_sizes[4];
    float* out    = (float*)d_out;
    float* out_ft = out;
    float* out_xt = out + (size_t)B * 64;

    dim3 grid(B / 8), block(256);
    hipLaunchKernelGGL(cmdnet_kernel, grid, block, 0, stream,
                       yt, Ht, sg, taui, delta, out_ft, out_xt, niter);
}

// Round 11
// 78.343 us; speedup vs baseline: 2.1053x; 1.3442x over previous
//
#include <hip/hip_runtime.h>

// CMDNet (M=2, m={-1,+1}, equal alpha) — MFMA HH + dot2/DPP matvec.
//
// Operating point: (256,4) ONLY (R2/R3/R5/R7/R8: >4 waves/EU always spills;
// gfx950 occupancy quantizes at 64/128/256 total regs).
//
// R10 lesson: own_pk[16] gathered inside the divergent `if (h==s)` region,
// live across phase 1's high-water mark, spilled even under a 128-reg cap
// (FETCH 128/WRITE 127 MB). Fix: per-batch LDS regions + ONE uniform gather
// AFTER phase 1 — own_pk never overlaps the MFMA staging registers and no
// long-lived value is defined under divergence.
//
// Loop (all R10-proven numerically): v_dot2_f32_f16 matvec on packed f16
// (0.5 prefolded), xor-16 via __builtin_amdgcn_permlane16_swap (direction-
// robust (A+B)-x recovery), exp2-domain G (v_exp_f32 is 2^x natively).
// Phase 1: HH = Ht^T Ht via v_mfma_f32_32x32x16_bf16, bf16 hi/lo split
// (err ~2^-17), ONE 16-AGPR acc reused across both batches; yH VALU partials.
// Tripwire: FETCH >> 68 MB or WRITE >> 6 MB => spill => revert phase 3 to
// R6's f32 matvec.

#define NRX 64
#define KSYM 32

typedef float  f32x16 __attribute__((ext_vector_type(16)));
typedef short  short8 __attribute__((ext_vector_type(8)));
typedef _Float16 h16x2 __attribute__((ext_vector_type(2)));

__device__ __forceinline__ float readlane_f(float v, int lane) {
    return __int_as_float(__builtin_amdgcn_readlane(__float_as_int(v), lane));
}
__device__ __forceinline__ unsigned cvt_pk_bf16(float a, float b) {
    unsigned r;
    asm("v_cvt_pk_bf16_f32 %0, %1, %2" : "=v"(r) : "v"(a), "v"(b));
    return r;
}
__device__ __forceinline__ int cvt_pk_f16(float a, float b) {  // RTZ pack
    int r;
    asm("v_cvt_pkrtz_f16_f32 %0, %1, %2" : "=v"(r) : "v"(a), "v"(b));
    return r;
}
template <int N>
__device__ __forceinline__ int dpp_ror_i(int v) {
    return __builtin_amdgcn_update_dpp(0, v, 0x120 + N, 0xF, 0xF, true);
}
__device__ __forceinline__ float dot2_f16(int a, int b, float c) {
#if __has_builtin(__builtin_amdgcn_fdot2)
    union { int i; h16x2 h; } ua, ub;
    ua.i = a; ub.i = b;
    return __builtin_amdgcn_fdot2(ua.h, ub.h, c, false);
#else
    float r = c;
    asm("v_dot2_f32_f16 %0, %1, %2, %0" : "+v"(r) : "v"(a), "v"(b));
    return r;
#endif
}
__device__ __forceinline__ float exp2_fast(float x) {
#if __has_builtin(__builtin_amdgcn_exp2f)
    return __builtin_amdgcn_exp2f(x);
#else
    float r; asm("v_exp_f32 %0, %1" : "=v"(r) : "v"(x)); return r;
#endif
}
__device__ __forceinline__ float xor16_f(float x) {
#if __has_builtin(__builtin_amdgcn_permlane16_swap)
    typedef unsigned uint2v __attribute__((ext_vector_type(2)));
    unsigned xi = __float_as_int(x);
    uint2v pr = __builtin_amdgcn_permlane16_swap(xi, xi, false, false);
    return (__uint_as_float(pr[0]) + __uint_as_float(pr[1])) - x;
#else
    return __int_as_float(
        __builtin_amdgcn_ds_swizzle(__float_as_int(x), 0x401F)); // xor 16
#endif
}

union FragU { unsigned u[4]; short8 s; };

__global__ __launch_bounds__(256, 4) void cmdnet_kernel(
    const float* __restrict__ yt,      // [B,64]
    const float* __restrict__ Ht,      // [B,64,32]
    const float* __restrict__ sigmat0, // [B]
    const float* __restrict__ taui,    // [niter+1]
    const float* __restrict__ delta,   // [niter]
    float* __restrict__ out_ft,        // [B,32,2]
    float* __restrict__ out_xt,        // [B,32]
    int niter)
{
    __shared__ __align__(16) float hhbuf[4][2][KSYM * KSYM]; // 32 KB: per-wave, per-batch
    __shared__ __align__(16) float ytL[4][2][NRX];           // 2 KB

    const int tid  = threadIdx.x;
    const int w    = tid >> 6;
    const int lane = tid & 63;
    const int k    = lane & 31;
    const int h    = lane >> 5;
    const int hi8  = h * 8;
    const int bb   = blockIdx.x * 8 + w * 2;
    const int b    = bb + h;
    const float LOG2E = 1.4426950408889634f;

    ytL[w][0][lane] = yt[(size_t)bb * NRX + lane];
    ytL[w][1][lane] = yt[(size_t)bb * NRX + NRX + lane];

    float dreg = 0.f, treg = 1.f;
    if (lane < niter) { dreg = delta[lane] * LOG2E; treg = fabsf(taui[lane + 1]); }

    float sig2 = sigmat0[b];
    sig2 *= sig2;

    float yhp0 = 0.f, yhp1 = 0.f;

    // ---- Phase 1: per batch s: MFMA HH (one shared acc) -> LDS region s ----
    #pragma unroll
    for (int s = 0; s < 2; ++s) {
        f32x16 acc;
        #pragma unroll
        for (int j = 0; j < 16; ++j) acc[j] = 0.f;

        const float* Hb = Ht + ((size_t)(bb + s)) * (NRX * KSYM);
        #pragma unroll
        for (int c = 0; c < 4; ++c) {
            const float* base = Hb + (c * 16 + hi8) * KSYM + k;
            float f[8];
            #pragma unroll
            for (int e = 0; e < 8; ++e) f[e] = base[e * KSYM];

            float4 ya = *reinterpret_cast<const float4*>(&ytL[w][s][c * 16 + hi8]);
            float4 yb = *reinterpret_cast<const float4*>(&ytL[w][s][c * 16 + hi8 + 4]);
            float yp = (s == 0) ? yhp0 : yhp1;
            yp = fmaf(ya.x, f[0], yp); yp = fmaf(ya.y, f[1], yp);
            yp = fmaf(ya.z, f[2], yp); yp = fmaf(ya.w, f[3], yp);
            yp = fmaf(yb.x, f[4], yp); yp = fmaf(yb.y, f[5], yp);
            yp = fmaf(yb.z, f[6], yp); yp = fmaf(yb.w, f[7], yp);
            if (s == 0) yhp0 = yp; else yhp1 = yp;

            FragU hiF, loF;
            #pragma unroll
            for (int p = 0; p < 4; ++p) {
                unsigned hp = cvt_pk_bf16(f[2*p], f[2*p+1]);
                float h0 = __uint_as_float(hp << 16);
                float h1 = __uint_as_float(hp & 0xffff0000u);
                loF.u[p] = cvt_pk_bf16(f[2*p] - h0, f[2*p+1] - h1);
                hiF.u[p] = hp;
            }
            acc = __builtin_amdgcn_mfma_f32_32x32x16_bf16(hiF.s, hiF.s, acc, 0, 0, 0);
            acc = __builtin_amdgcn_mfma_f32_32x32x16_bf16(hiF.s, loF.s, acc, 0, 0, 0);
            acc = __builtin_amdgcn_mfma_f32_32x32x16_bf16(loF.s, hiF.s, acc, 0, 0, 0);
        }

        // acc -> LDS region s (C/D layout: col=lane&31, row=(j&3)+8*(j>>2)+4*h)
        float* buf_s = &hhbuf[w][s][0];
        #pragma unroll
        for (int j = 0; j < 16; ++j) {
            int row = (j & 3) + 8 * (j >> 2) + 4 * h;
            buf_s[row * 32 + k] = acc[j];
        }
    }

    // ---- Phase 2: UNIFORM gather (no divergence): lane (h,k) reads its row
    //      from region h, diagonal-permuted (same dpp ctrl as the loop),
    //      scaled by 0.5, packed f16. own_pk starts life AFTER staging dies.
    int own_pk[16];
    {
        const int low4 = k & 15;
        const float* rowp = &hhbuf[w][h][k * 32];
        own_pk[0] = cvt_pk_f16(0.5f * rowp[k], 0.5f * rowp[k ^ 16]);
        #define GATH(J) { \
            int idx = dpp_ror_i<J>(low4); \
            own_pk[J] = cvt_pk_f16(0.5f * rowp[(k & 16) | idx], \
                                   0.5f * rowp[((k & 16) ^ 16) | idx]); }
        GATH(1)  GATH(2)  GATH(3)  GATH(4)  GATH(5)
        GATH(6)  GATH(7)  GATH(8)  GATH(9)  GATH(10)
        GATH(11) GATH(12) GATH(13) GATH(14) GATH(15)
        #undef GATH
    }

    float yh0 = yhp0 + __shfl_xor(yhp0, 32, 64);
    float yh1 = yhp1 + __shfl_xor(yhp1, 32, 64);
    float yh  = 0.5f * (h ? yh1 : yh0);   // pre-halved to match own_pk scale

    // ---- Phase 3: iterations ----
    float tau = fabsf(taui[0]);
    float Gl0 = 0.f, Gl1 = 0.f;           // G * log2e
    float xt = 0.f;

    for (int i = 0; i < niter; ++i) {
        float d2       = readlane_f(dreg, i);   // delta*log2e
        float tau_next = readlane_f(treg, i);

        float xts = xor16_f(xt);
        int xpk = cvt_pk_f16(xt, xts);

        float a0 = -yh, a1 = 0.f, a2 = 0.f, a3 = 0.f;
        a0 = dot2_f16(own_pk[0], xpk, a0);
        #define STEP(J) { \
            int xr = dpp_ror_i<J>(xpk); \
            float& aa = ((J) & 3) == 0 ? a0 : ((J) & 3) == 1 ? a1 : ((J) & 3) == 2 ? a2 : a3; \
            aa = dot2_f16(own_pk[J], xr, aa); }
        STEP(1)  STEP(2)  STEP(3)  STEP(4)  STEP(5)
        STEP(6)  STEP(7)  STEP(8)  STEP(9)  STEP(10)
        STEP(11) STEP(12) STEP(13) STEP(14) STEP(15)
        #undef STEP
        float r = (a0 + a1) + (a2 + a3);   // = 0.5*(xHH - yH)

        float t  = fmaf(-xt, xt, 1.0f);
        float p  = tau * t * r;            // = 2*tau*ft0*ft1*(xHH-yH)
        float e0 = exp2_fast(-Gl0);        // = exp(-G0)
        float e1 = exp2_fast(-Gl1);
        float g0 = fmaf(sig2, 1.f - e0, -p);
        float g1 = fmaf(sig2, 1.f - e1,  p);
        Gl0 = fmaf(-d2, g0, Gl0);
        Gl1 = fmaf(-d2, g1, Gl1);

        tau = tau_next;
        float z2 = tau * (Gl1 - Gl0);      // = log2e * z
        float ez = exp2_fast(-fabsf(z2));  // = exp(-|z|)
        float sg = __builtin_amdgcn_rcpf(1.f + ez);
        float m  = (1.f - ez) * sg;        // |tanh(z/2)|
        xt = __builtin_copysignf(m, z2);
    }

    // ---- outputs: ft1 = (1+xt)/2, ft0 = (1-xt)/2 ----
    float ft1 = fmaf(0.5f, xt, 0.5f);
    float ft0 = 1.f - ft1;
    float2 f2 = make_float2(ft0, ft1);
    reinterpret_cast<float2*>(out_ft)[(size_t)b * KSYM + k] = f2;
    out_xt[(size_t)b * KSYM + k] = xt;
}

extern "C" void kernel_launch(void* const* d_in, const int* in_sizes, int n_in,
                              void* d_out, int out_size, void* d_ws, size_t ws_size,
                              hipStream_t stream) {
    const float* yt    = (const float*)d_in[0];
    const float* Ht    = (const float*)d_in[1];
    const float* sg    = (const float*)d_in[2];
    const float* taui  = (const float*)d_in[3];
    const float* delta = (const float*)d_in[4];
    int B     = in_sizes[2];
    int niter = in_sizes[4];
    float* out    = (float*)d_out;
    float* out_ft = out;
    float* out_xt = out + (size_t)B * 64;

    dim3 grid(B / 8), block(256);
    hipLaunchKernelGGL(cmdnet_kernel, grid, block, 0, stream,
                       yt, Ht, sg, taui, delta, out_ft, out_xt, niter);
}